// Round 3
// baseline (203.144 us; speedup 1.0000x reference)
//
#include <hip/hip_runtime.h>
#include <stdint.h>

#define H_ 16
#define S_ 4096
#define D_ 64
#define ROWSTRIDE (H_ * D_)   // 1024 floats between consecutive s rows
#define BQW 32                // q rows per wave
#define BQ 128                // q rows per block (4 waves)
#define BK 64                 // keys per main-loop iteration
#define NT (S_ / BK)          // 64 key tiles
#define TILE_USH (BK * D_)    // 4096 ushorts per packed 64x64 bf16 tile
#define LP 72
#define LK 72
#define QSCALE (0.125f * 1.44269504088896340736f)  // sm_scale * log2(e)
#define LOG2E 1.44269504088896340736f
#define SM_SCALE 0.125f

typedef unsigned short ushort_t;
typedef __attribute__((ext_vector_type(8))) __bf16 bf16x8;
typedef __attribute__((ext_vector_type(4))) float floatx4;
typedef __attribute__((ext_vector_type(16))) float floatx16;
typedef __attribute__((ext_vector_type(8))) unsigned short ushortx8;
typedef __attribute__((ext_vector_type(4))) unsigned short ushortx4;

#if __has_builtin(__builtin_amdgcn_exp2f)
#define EXP2F(x) __builtin_amdgcn_exp2f(x)
#else
#define EXP2F(x) exp2f(x)
#endif

__device__ inline unsigned short f2bf(float x) {   // RNE fp32->bf16
    union { float f; unsigned int u; } c; c.f = x;
    unsigned int r = c.u + 0x7fffu + ((c.u >> 16) & 1u);
    return (unsigned short)(r >> 16);
}
__device__ inline bf16x8 as_bf16x8(ushortx8 v) {
    union { ushortx8 s; bf16x8 b; } c; c.s = v; return c.b;
}
__device__ inline bf16x8 bf16x8_from_u32(uint32_t a, uint32_t b, uint32_t c, uint32_t d) {
    union { uint32_t u[4]; bf16x8 b; } x; x.u[0]=a; x.u[1]=b; x.u[2]=c; x.u[3]=d; return x.b;
}
__device__ inline void glds16(const void* g, void* l) {
    __builtin_amdgcn_global_load_lds(
        (const __attribute__((address_space(1))) void*)g,
        (__attribute__((address_space(3))) void*)l, 16, 0, 0);
}

// ---------------------------------------------------------------------------
// Pre-pass (unchanged from R2): K -> bf16 tiles [h][tile][row*64 + (chunk^(row&7))*8]
// V -> bf16 transposed tiles, same XOR-16B-chunk swizzle.
// ---------------------------------------------------------------------------
__global__ __launch_bounds__(256)
void pack_kv(const float* __restrict__ K, const float* __restrict__ V,
             ushort_t* __restrict__ Kp, ushort_t* __restrict__ Vp) {
    __shared__ ushort_t lT[D_ * 88];
    const int tid = threadIdx.x;
    const int h = blockIdx.x & (H_ - 1);
    const int tile = blockIdx.x >> 4;
    ushort_t* kout = Kp + (size_t)(h * NT + tile) * TILE_USH;
    ushort_t* vout = Vp + (size_t)(h * NT + tile) * TILE_USH;
    #pragma unroll
    for (int p = 0; p < 4; ++p) {
        int idx = tid + p * 256;
        int row = idx >> 4;
        int d4 = (idx & 15) * 4;
        const float* kp = K + (size_t)(tile * BK + row) * ROWSTRIDE + h * D_ + d4;
        float4 kv = *(const float4*)kp;
        ushortx4 ku;
        ku[0] = f2bf(kv.x); ku[1] = f2bf(kv.y); ku[2] = f2bf(kv.z); ku[3] = f2bf(kv.w);
        *(ushortx4*)&kout[row * 64 + (((d4 >> 3) ^ (row & 7)) * 8) + (d4 & 7)] = ku;
        const float* vp = V + (size_t)(tile * BK + row) * ROWSTRIDE + h * D_ + d4;
        float4 vv = *(const float4*)vp;
        lT[(d4 + 0) * 88 + row] = f2bf(vv.x);
        lT[(d4 + 1) * 88 + row] = f2bf(vv.y);
        lT[(d4 + 2) * 88 + row] = f2bf(vv.z);
        lT[(d4 + 3) * 88 + row] = f2bf(vv.w);
    }
    __syncthreads();
    #pragma unroll
    for (int p = 0; p < 2; ++p) {
        int cid = tid + p * 256;
        int rowd = cid >> 3;
        int j = cid & 7;
        ushortx8 val = *(ushortx8*)&lT[rowd * 88 + j * 8];
        *(ushortx8*)&vout[rowd * 64 + ((j ^ (rowd & 7)) * 8)] = val;
    }
}

// ---------------------------------------------------------------------------
// Main kernel, 32x32x16 MFMA, swapped operands:
//   S^T = K * Q^T   (A = K from LDS, B = Q^T in registers)
//   O^T = V^T * P^T (A = V^T from LDS, B = P^T assembled IN REGISTERS from
//                    S^T's C-layout via one shfl_xor(32) per packed quad)
// C-layout (32x32): col = n = lane&31, row = m = (reg&3)+8*(reg>>2)+4*(lane>>5).
// P^T B-operand needs k=key=(lane>>5)*8+j, n=q=lane&31: q already in lane&31;
// key j=0..3 come from the g2=0 half's reg-quad (2*ci+g2_target), j=4..7 from
// the g2=1 half's same quad -> exchange quads with shfl_xor 32 + cndmask.
// No P LDS round-trip; fragment reads amortize over 32 kFLOP MFMAs.
// ---------------------------------------------------------------------------
__global__ __launch_bounds__(256, 2)
void usp_attn_fa3(const float* __restrict__ Q, const ushort_t* __restrict__ Kp,
                  const ushort_t* __restrict__ Vp, float* __restrict__ O) {
    __shared__ ushort_t lK[TILE_USH];    // K tile  [key][d]  bf16, swizzled
    __shared__ ushort_t lVT[TILE_USH];   // V^T tile [d][key] bf16, swizzled

    const int tid = threadIdx.x;
    const int lane = tid & 63;
    const int wv = tid >> 6;
    const int h = blockIdx.x & (H_ - 1);
    const int qt = blockIdx.x >> 4;
    const int q0 = qt * BQ + wv * BQW;
    const int l31 = lane & 31;
    const int g2 = lane >> 5;

    // Q^T B-frags: B[k: d=c*16+g2*8+j][n: q=l31], pre-scaled into log2 domain
    bf16x8 qf[4];
    {
        const float* qp = Q + (size_t)(q0 + l31) * ROWSTRIDE + h * D_ + g2 * 8;
        #pragma unroll
        for (int c = 0; c < 4; ++c) {
            ushortx8 u;
            #pragma unroll
            for (int j = 0; j < 8; ++j) u[j] = f2bf(qp[c * 16 + j] * QSCALE);
            qf[c] = as_bf16x8(u);
        }
    }

    floatx16 o[2] = {{0,0,0,0,0,0,0,0,0,0,0,0,0,0,0,0},
                     {0,0,0,0,0,0,0,0,0,0,0,0,0,0,0,0}};  // O^T, m-tiles d:0-31,32-63
    float rs = 0.f;                                        // lane's partial denom (one q)
    const ushort_t* kbase = Kp + (size_t)h * NT * TILE_USH;
    const ushort_t* vbase = Vp + (size_t)h * NT * TILE_USH;

    for (int kt = 0; kt < NT; ++kt) {
        __syncthreads();
        {
            const ushort_t* gk = kbase + (size_t)kt * TILE_USH;
            const ushort_t* gv = vbase + (size_t)kt * TILE_USH;
            #pragma unroll
            for (int i = 0; i < 2; ++i) {
                int seg = wv * 2 + i;
                glds16(gk + seg * 512 + lane * 8, &lK[seg * 512]);
                glds16(gv + seg * 512 + lane * 8, &lVT[seg * 512]);
            }
        }
        __syncthreads();

        // --- S^T = K Q^T : 2 m-tiles (keys) x 4 k-chunks (d)
        floatx16 st[2];
        #pragma unroll
        for (int mk = 0; mk < 2; ++mk) {
            floatx16 acc = {0,0,0,0,0,0,0,0,0,0,0,0,0,0,0,0};
            int row = mk * 32 + l31;
            int sx = row & 7;
            #pragma unroll
            for (int c = 0; c < 4; ++c) {
                bf16x8 kf = as_bf16x8(*(const ushortx8*)&lK[row * 64 + (((2 * c + g2) ^ sx) * 8)]);
                acc = __builtin_amdgcn_mfma_f32_32x32x16_bf16(kf, qf[c], acc, 0, 0, 0);
            }
            st[mk] = acc;
        }

        // --- P = exp2(S'); pack bf16 pairs; accumulate denominator
        uint32_t qd[2][8];   // [mk][quad*2 + half]: quad qn = regs 4qn..4qn+3
        #pragma unroll
        for (int mk = 0; mk < 2; ++mk) {
            #pragma unroll
            for (int i = 0; i < 8; ++i) {
                float p0 = EXP2F(st[mk][2 * i]);
                float p1 = EXP2F(st[mk][2 * i + 1]);
                rs += p0 + p1;
                qd[mk][i] = (uint32_t)f2bf(p0) | ((uint32_t)f2bf(p1) << 16);
            }
        }

        // --- O^T += V^T P^T : 4 key-chunks x 2 d-tiles
        #pragma unroll
        for (int kc = 0; kc < 4; ++kc) {
            int mk = kc >> 1, ci = kc & 1;
            uint32_t a0 = qd[mk][ci * 4 + 0], a1 = qd[mk][ci * 4 + 1];  // quad 2ci
            uint32_t b0 = qd[mk][ci * 4 + 2], b1 = qd[mk][ci * 4 + 3];  // quad 2ci+1
            uint32_t ra0 = (uint32_t)__shfl_xor((int)a0, 32, 64);
            uint32_t ra1 = (uint32_t)__shfl_xor((int)a1, 32, 64);
            uint32_t rb0 = (uint32_t)__shfl_xor((int)b0, 32, 64);
            uint32_t rb1 = (uint32_t)__shfl_xor((int)b1, 32, 64);
            // j0-3 from lower-half's quad(2ci+g2); j4-7 from upper-half's quad(2ci+g2)
            uint32_t lo0 = g2 ? rb0 : a0, lo1 = g2 ? rb1 : a1;
            uint32_t hi0 = g2 ? b0 : ra0, hi1 = g2 ? b1 : ra1;
            bf16x8 pf = bf16x8_from_u32(lo0, lo1, hi0, hi1);
            #pragma unroll
            for (int md = 0; md < 2; ++md) {
                int row = md * 32 + l31;
                bf16x8 vf = as_bf16x8(*(const ushortx8*)&lVT[row * 64 + (((2 * kc + g2) ^ (row & 7)) * 8)]);
                o[md] = __builtin_amdgcn_mfma_f32_32x32x16_bf16(vf, pf, o[md], 0, 0, 0);
            }
        }
    }

    // --- epilogue: complete denom (partner holds the other 32 keys' sum), store
    rs += __shfl_xor(rs, 32, 64);
    float inv = 1.f / rs;
    float* op = O + (size_t)(q0 + l31) * ROWSTRIDE + h * D_;
    #pragma unroll
    for (int md = 0; md < 2; ++md) {
        #pragma unroll
        for (int rq = 0; rq < 4; ++rq) {
            int d0 = md * 32 + rq * 8 + 4 * g2;   // C row = (reg&3)+8*(reg>>2)+4*g2
            float4 w;
            w.x = o[md][4 * rq + 0] * inv;
            w.y = o[md][4 * rq + 1] * inv;
            w.z = o[md][4 * rq + 2] * inv;
            w.w = o[md][4 * rq + 3] * inv;
            *(float4*)&op[d0] = w;
        }
    }
}

// ---------------------------------------------------------------------------
// Fallback (proven R1 kernel) if ws_size can't hold packed K/V.
// ---------------------------------------------------------------------------
__global__ __launch_bounds__(256, 2)
void usp_attn_fa(const float* __restrict__ Q, const float* __restrict__ K,
                 const float* __restrict__ V, float* __restrict__ O) {
    __shared__ unsigned short fK[BK * LK];
    __shared__ unsigned short fVT[D_ * LK];
    __shared__ unsigned short fP[4 * 16 * LP];
    const int tid = threadIdx.x;
    const int lane = tid & 63;
    const int wv = tid >> 6;
    const int h = blockIdx.x & (H_ - 1);
    const int qt = blockIdx.x >> 4;
    const int q0 = qt * 64 + wv * 16;
    const int m16 = lane & 15;
    const int g = lane >> 4;
    typedef __attribute__((ext_vector_type(4))) float f4;
    bf16x8 qf[2];
    {
        const float* qp = Q + (size_t)(q0 + m16) * ROWSTRIDE + h * D_ + g * 8;
        for (int c = 0; c < 2; ++c) {
            ushortx8 u;
            #pragma unroll
            for (int j = 0; j < 8; ++j) u[j] = f2bf(qp[c * 32 + j]);
            qf[c] = as_bf16x8(u);
        }
    }
    f4 o[4] = {{0,0,0,0},{0,0,0,0},{0,0,0,0},{0,0,0,0}};
    float mrow[4] = {-1e30f,-1e30f,-1e30f,-1e30f};
    float lrow[4] = {0.f,0.f,0.f,0.f};
    unsigned short* myP = &fP[wv * 16 * LP];
    for (int k0 = 0; k0 < S_; k0 += BK) {
        __syncthreads();
        #pragma unroll
        for (int p = 0; p < 4; ++p) {
            int idx = tid + p * 256;
            int row = idx >> 4;
            int c4 = (idx & 15) * 4;
            const float* kp = K + (size_t)(k0 + row) * ROWSTRIDE + h * D_ + c4;
            float4 kv = *(const float4*)kp;
            ushortx4 ku;
            ku[0] = f2bf(kv.x); ku[1] = f2bf(kv.y); ku[2] = f2bf(kv.z); ku[3] = f2bf(kv.w);
            *(ushortx4*)&fK[row * LK + c4] = ku;
            const float* vp = V + (size_t)(k0 + row) * ROWSTRIDE + h * D_ + c4;
            float4 vv = *(const float4*)vp;
            fVT[(c4 + 0) * LK + row] = f2bf(vv.x);
            fVT[(c4 + 1) * LK + row] = f2bf(vv.y);
            fVT[(c4 + 2) * LK + row] = f2bf(vv.z);
            fVT[(c4 + 3) * LK + row] = f2bf(vv.w);
        }
        __syncthreads();
        f4 s[4];
        #pragma unroll
        for (int t = 0; t < 4; ++t) {
            f4 acc = {0,0,0,0};
            #pragma unroll
            for (int c = 0; c < 2; ++c) {
                bf16x8 kf = as_bf16x8(*(ushortx8*)&fK[(t * 16 + m16) * LK + c * 32 + g * 8]);
                acc = __builtin_amdgcn_mfma_f32_16x16x32_bf16(qf[c], kf, acc, 0, 0, 0);
            }
            s[t] = acc * SM_SCALE;
        }
        float mnew[4], rsum[4];
        #pragma unroll
        for (int r = 0; r < 4; ++r) {
            float pm = fmaxf(fmaxf(s[0][r], s[1][r]), fmaxf(s[2][r], s[3][r]));
            #pragma unroll
            for (int msk = 1; msk <= 8; msk <<= 1) pm = fmaxf(pm, __shfl_xor(pm, msk, 64));
            mnew[r] = fmaxf(mrow[r], pm);
            rsum[r] = 0.f;
        }
        #pragma unroll
        for (int t = 0; t < 4; ++t) {
            #pragma unroll
            for (int r = 0; r < 4; ++r) {
                float p = EXP2F((s[t][r] - mnew[r]) * LOG2E);
                rsum[r] += p;
                myP[(g * 4 + r) * LP + t * 16 + m16] = f2bf(p);
            }
        }
        #pragma unroll
        for (int r = 0; r < 4; ++r) {
            #pragma unroll
            for (int msk = 1; msk <= 8; msk <<= 1) rsum[r] += __shfl_xor(rsum[r], msk, 64);
            float alpha = EXP2F((mrow[r] - mnew[r]) * LOG2E);
            lrow[r] = lrow[r] * alpha + rsum[r];
            mrow[r] = mnew[r];
            o[0][r] *= alpha; o[1][r] *= alpha; o[2][r] *= alpha; o[3][r] *= alpha;
        }
        #pragma unroll
        for (int c = 0; c < 2; ++c) {
            bf16x8 pf = as_bf16x8(*(ushortx8*)&myP[m16 * LP + c * 32 + g * 8]);
            #pragma unroll
            for (int t = 0; t < 4; ++t) {
                bf16x8 vf = as_bf16x8(*(ushortx8*)&fVT[(t * 16 + m16) * LK + c * 32 + g * 8]);
                o[t] = __builtin_amdgcn_mfma_f32_16x16x32_bf16(pf, vf, o[t], 0, 0, 0);
            }
        }
    }
    float* op = O + (size_t)q0 * ROWSTRIDE + h * D_;
    #pragma unroll
    for (int r = 0; r < 4; ++r) {
        float inv = 1.f / lrow[r];
        int row = g * 4 + r;
        #pragma unroll
        for (int t = 0; t < 4; ++t)
            op[(size_t)row * ROWSTRIDE + t * 16 + m16] = o[t][r] * inv;
    }
}

extern "C" void kernel_launch(void* const* d_in, const int* in_sizes, int n_in,
                              void* d_out, int out_size, void* d_ws, size_t ws_size,
                              hipStream_t stream) {
    const float* Q = (const float*)d_in[0];
    const float* K = (const float*)d_in[1];
    const float* V = (const float*)d_in[2];
    float* O = (float*)d_out;
    const size_t packed = (size_t)H_ * NT * TILE_USH;
    if (ws_size >= 2 * packed * sizeof(ushort_t)) {
        ushort_t* Kp = (ushort_t*)d_ws;
        ushort_t* Vp = Kp + packed;
        pack_kv<<<dim3(H_ * NT), dim3(256), 0, stream>>>(K, V, Kp, Vp);
        usp_attn_fa3<<<dim3(H_ * (S_ / BQ)), dim3(256), 0, stream>>>(Q, Kp, Vp, O);
    } else {
        usp_attn_fa<<<dim3(H_ * (S_ / 64)), dim3(256), 0, stream>>>(Q, K, V, O);
    }
}

// Round 4
// 198.879 us; speedup vs baseline: 1.0214x; 1.0214x over previous
//
#include <hip/hip_runtime.h>
#include <stdint.h>

#define H_ 16
#define S_ 4096
#define D_ 64
#define ROWSTRIDE (H_ * D_)   // 1024 floats between consecutive s rows
#define BQW 32                // q rows per wave
#define BQ 64                 // q rows per block (2 q-subtiles x 2 key-half waves)
#define BK 64                 // keys per tile
#define NT (S_ / BK)          // 64 key tiles
#define NH2 (NT / 2)          // 32 tiles per key-half
#define TILE_USH (BK * D_)    // 4096 ushorts per packed 64x64 bf16 tile
#define LP 72
#define LK 72
#define QSCALE (0.125f * 1.44269504088896340736f)  // sm_scale * log2(e)
#define LOG2E 1.44269504088896340736f
#define SM_SCALE 0.125f

typedef unsigned short ushort_t;
typedef __attribute__((ext_vector_type(8))) __bf16 bf16x8;
typedef __attribute__((ext_vector_type(2))) __bf16 bf16x2;
typedef __attribute__((ext_vector_type(4))) float floatx4;
typedef __attribute__((ext_vector_type(16))) float floatx16;
typedef __attribute__((ext_vector_type(8))) unsigned short ushortx8;
typedef __attribute__((ext_vector_type(4))) unsigned short ushortx4;

#if __has_builtin(__builtin_amdgcn_exp2f)
#define EXP2F(x) __builtin_amdgcn_exp2f(x)
#else
#define EXP2F(x) exp2f(x)
#endif

__device__ inline unsigned short f2bf(float x) {   // RNE fp32->bf16
    union { float f; unsigned int u; } c; c.f = x;
    unsigned int r = c.u + 0x7fffu + ((c.u >> 16) & 1u);
    return (unsigned short)(r >> 16);
}
// packed 2xfp32 -> 2xbf16 in a u32; single VALU op on gfx950 if available
__device__ inline uint32_t pack_bf16(float a, float b) {
#if __has_builtin(__builtin_amdgcn_cvt_pk_bf16_f32)
    union { bf16x2 v; uint32_t u; } c;
    c.v = __builtin_amdgcn_cvt_pk_bf16_f32(a, b);
    return c.u;
#else
    return (uint32_t)f2bf(a) | ((uint32_t)f2bf(b) << 16);
#endif
}
__device__ inline bf16x8 as_bf16x8(ushortx8 v) {
    union { ushortx8 s; bf16x8 b; } c; c.s = v; return c.b;
}
__device__ inline bf16x8 bf16x8_from_u32(uint32_t a, uint32_t b, uint32_t c, uint32_t d) {
    union { uint32_t u[4]; bf16x8 b; } x; x.u[0]=a; x.u[1]=b; x.u[2]=c; x.u[3]=d; return x.b;
}
__device__ inline void glds16(const void* g, void* l) {
    __builtin_amdgcn_global_load_lds(
        (const __attribute__((address_space(1))) void*)g,
        (__attribute__((address_space(3))) void*)l, 16, 0, 0);
}

// ---------------------------------------------------------------------------
// Pre-pass (unchanged): K -> bf16 tiles [h][tile][row*64 + ((chunk)^(row&7))*8],
// V -> bf16 transposed tiles, same XOR-16B-chunk swizzle.
// ---------------------------------------------------------------------------
__global__ __launch_bounds__(256)
void pack_kv(const float* __restrict__ K, const float* __restrict__ V,
             ushort_t* __restrict__ Kp, ushort_t* __restrict__ Vp) {
    __shared__ ushort_t lT[D_ * 88];
    const int tid = threadIdx.x;
    const int h = blockIdx.x & (H_ - 1);
    const int tile = blockIdx.x >> 4;
    ushort_t* kout = Kp + (size_t)(h * NT + tile) * TILE_USH;
    ushort_t* vout = Vp + (size_t)(h * NT + tile) * TILE_USH;
    #pragma unroll
    for (int p = 0; p < 4; ++p) {
        int idx = tid + p * 256;
        int row = idx >> 4;
        int d4 = (idx & 15) * 4;
        const float* kp = K + (size_t)(tile * BK + row) * ROWSTRIDE + h * D_ + d4;
        float4 kv = *(const float4*)kp;
        ushortx4 ku;
        ku[0] = f2bf(kv.x); ku[1] = f2bf(kv.y); ku[2] = f2bf(kv.z); ku[3] = f2bf(kv.w);
        *(ushortx4*)&kout[row * 64 + (((d4 >> 3) ^ (row & 7)) * 8) + (d4 & 7)] = ku;
        const float* vp = V + (size_t)(tile * BK + row) * ROWSTRIDE + h * D_ + d4;
        float4 vv = *(const float4*)vp;
        lT[(d4 + 0) * 88 + row] = f2bf(vv.x);
        lT[(d4 + 1) * 88 + row] = f2bf(vv.y);
        lT[(d4 + 2) * 88 + row] = f2bf(vv.z);
        lT[(d4 + 3) * 88 + row] = f2bf(vv.w);
    }
    __syncthreads();
    #pragma unroll
    for (int p = 0; p < 2; ++p) {
        int cid = tid + p * 256;
        int rowd = cid >> 3;
        int j = cid & 7;
        ushortx8 val = *(ushortx8*)&lT[rowd * 88 + j * 8];
        *(ushortx8*)&vout[rowd * 64 + ((j ^ (rowd & 7)) * 8)] = val;
    }
}

// ---------------------------------------------------------------------------
// Main kernel R4: 32x32x16 MFMA swapped-operand form (S^T = K Q^T,
// O^T = V^T P^T with register-shuffle P^T assembly), PLUS in-block K-split:
// wave w = qsub (w&1) x khalf (w>>1). Fixed-max softmax is associative over
// keys, so each wave processes 32 of the 64 key tiles; partial O / denom
// combined through LDS in the epilogue. 16 waves/CU (vs 8 in R3) for latency
// hiding; per-step both halves' tiles staged cooperatively (32 KB LDS).
// ---------------------------------------------------------------------------
__global__ __launch_bounds__(256, 4)
void usp_attn_fa4(const float* __restrict__ Q, const ushort_t* __restrict__ Kp,
                  const ushort_t* __restrict__ Vp, float* __restrict__ O) {
    __shared__ __attribute__((aligned(16))) ushort_t smem[4 * TILE_USH];  // 32 KB

    ushort_t* lKa  = smem;                  // key-half 0: K tile
    ushort_t* lVTa = smem + TILE_USH;       //             V^T tile
    ushort_t* lKb  = smem + 2 * TILE_USH;   // key-half 1: K tile
    ushort_t* lVTb = smem + 3 * TILE_USH;   //             V^T tile

    const int tid = threadIdx.x;
    const int lane = tid & 63;
    const int wv = tid >> 6;
    const int qsub = wv & 1;
    const int khalf = wv >> 1;
    const int h = blockIdx.x & (H_ - 1);
    const int qt = blockIdx.x >> 4;
    const int q0 = qt * BQ + qsub * BQW;
    const int l31 = lane & 31;
    const int g2 = lane >> 5;

    // Q^T B-frags: B[k: d=c*16+g2*8+j][n: q=l31], pre-scaled into log2 domain
    bf16x8 qf[4];
    {
        const float* qp = Q + (size_t)(q0 + l31) * ROWSTRIDE + h * D_ + g2 * 8;
        #pragma unroll
        for (int c = 0; c < 4; ++c) {
            ushortx8 u;
            #pragma unroll
            for (int j = 0; j < 8; ++j) u[j] = f2bf(qp[c * 16 + j] * QSCALE);
            qf[c] = as_bf16x8(u);
        }
    }

    floatx16 o[2] = {{0,0,0,0,0,0,0,0,0,0,0,0,0,0,0,0},
                     {0,0,0,0,0,0,0,0,0,0,0,0,0,0,0,0}};  // O^T partial
    float rs = 0.f;                                        // partial denom
    const ushort_t* kbase = Kp + (size_t)h * NT * TILE_USH;
    const ushort_t* vbase = Vp + (size_t)h * NT * TILE_USH;
    const ushort_t* myK  = khalf ? lKb : lKa;
    const ushort_t* myVT = khalf ? lVTb : lVTa;

    for (int s = 0; s < NH2; ++s) {
        __syncthreads();                    // previous step's consumers done
        {
            const ushort_t* gka = kbase + (size_t)s * TILE_USH;
            const ushort_t* gva = vbase + (size_t)s * TILE_USH;
            const ushort_t* gkb = kbase + (size_t)(NH2 + s) * TILE_USH;
            const ushort_t* gvb = vbase + (size_t)(NH2 + s) * TILE_USH;
            #pragma unroll
            for (int i = 0; i < 2; ++i) {
                int seg = wv * 2 + i;       // wave-uniform
                glds16(gka + seg * 512 + lane * 8, &lKa[seg * 512]);
                glds16(gva + seg * 512 + lane * 8, &lVTa[seg * 512]);
                glds16(gkb + seg * 512 + lane * 8, &lKb[seg * 512]);
                glds16(gvb + seg * 512 + lane * 8, &lVTb[seg * 512]);
            }
        }
        __syncthreads();                    // publish (drains vmcnt)

        // --- S^T = K Q^T : 2 m-tiles (keys) x 4 k-chunks (d)
        floatx16 st[2];
        #pragma unroll
        for (int mk = 0; mk < 2; ++mk) {
            floatx16 acc = {0,0,0,0,0,0,0,0,0,0,0,0,0,0,0,0};
            int row = mk * 32 + l31;
            int sx = row & 7;
            #pragma unroll
            for (int c = 0; c < 4; ++c) {
                bf16x8 kf = as_bf16x8(*(const ushortx8*)&myK[row * 64 + (((2 * c + g2) ^ sx) * 8)]);
                acc = __builtin_amdgcn_mfma_f32_32x32x16_bf16(kf, qf[c], acc, 0, 0, 0);
            }
            st[mk] = acc;
        }

        // --- P = exp2(S'); pack bf16 pairs; accumulate denominator
        uint32_t qd[2][8];
        #pragma unroll
        for (int mk = 0; mk < 2; ++mk) {
            #pragma unroll
            for (int i = 0; i < 8; ++i) {
                float p0 = EXP2F(st[mk][2 * i]);
                float p1 = EXP2F(st[mk][2 * i + 1]);
                rs += p0 + p1;
                qd[mk][i] = pack_bf16(p0, p1);
            }
        }

        // --- O^T += V^T P^T : 4 key-chunks x 2 d-tiles (P^T via shfl_xor 32)
        #pragma unroll
        for (int kc = 0; kc < 4; ++kc) {
            int mk = kc >> 1, ci = kc & 1;
            uint32_t a0 = qd[mk][ci * 4 + 0], a1 = qd[mk][ci * 4 + 1];
            uint32_t b0 = qd[mk][ci * 4 + 2], b1 = qd[mk][ci * 4 + 3];
            uint32_t ra0 = (uint32_t)__shfl_xor((int)a0, 32, 64);
            uint32_t ra1 = (uint32_t)__shfl_xor((int)a1, 32, 64);
            uint32_t rb0 = (uint32_t)__shfl_xor((int)b0, 32, 64);
            uint32_t rb1 = (uint32_t)__shfl_xor((int)b1, 32, 64);
            uint32_t lo0 = g2 ? rb0 : a0, lo1 = g2 ? rb1 : a1;
            uint32_t hi0 = g2 ? b0 : ra0, hi1 = g2 ? b1 : ra1;
            bf16x8 pf = bf16x8_from_u32(lo0, lo1, hi0, hi1);
            #pragma unroll
            for (int md = 0; md < 2; ++md) {
                int row = md * 32 + l31;
                bf16x8 vf = as_bf16x8(*(const ushortx8*)&myVT[row * 64 + (((2 * kc + g2) ^ (row & 7)) * 8)]);
                o[md] = __builtin_amdgcn_mfma_f32_32x32x16_bf16(vf, pf, o[md], 0, 0, 0);
            }
        }
    }

    // --- epilogue: combine key-half partials through LDS, then store.
    rs += __shfl_xor(rs, 32, 64);           // full denom for this key-half
    float* part = (float*)smem;             // overlay partial regions on tile LDS
    float* pbase = part + qsub * 2112;      // 2048 O-floats + 32 denom + pad
    __syncthreads();                        // tile consumers done; safe to overlay
    if (khalf == 1) {
        #pragma unroll
        for (int md = 0; md < 2; ++md) {
            #pragma unroll
            for (int rq = 0; rq < 4; ++rq) {
                float4 w4;
                w4.x = o[md][4 * rq + 0]; w4.y = o[md][4 * rq + 1];
                w4.z = o[md][4 * rq + 2]; w4.w = o[md][4 * rq + 3];
                *(float4*)&pbase[(md * 4 + rq) * 256 + lane * 4] = w4;
            }
        }
        if (g2 == 0) pbase[2048 + l31] = rs;
    }
    __syncthreads();
    if (khalf == 0) {
        #pragma unroll
        for (int md = 0; md < 2; ++md) {
            #pragma unroll
            for (int rq = 0; rq < 4; ++rq) {
                float4 w4 = *(const float4*)&pbase[(md * 4 + rq) * 256 + lane * 4];
                o[md][4 * rq + 0] += w4.x; o[md][4 * rq + 1] += w4.y;
                o[md][4 * rq + 2] += w4.z; o[md][4 * rq + 3] += w4.w;
            }
        }
        float inv = 1.f / (rs + pbase[2048 + l31]);
        float* op = O + (size_t)(q0 + l31) * ROWSTRIDE + h * D_;
        #pragma unroll
        for (int md = 0; md < 2; ++md) {
            #pragma unroll
            for (int rq = 0; rq < 4; ++rq) {
                int d0 = md * 32 + rq * 8 + 4 * g2;   // C row = (reg&3)+8*(reg>>2)+4*g2
                float4 w;
                w.x = o[md][4 * rq + 0] * inv;
                w.y = o[md][4 * rq + 1] * inv;
                w.z = o[md][4 * rq + 2] * inv;
                w.w = o[md][4 * rq + 3] * inv;
                *(float4*)&op[d0] = w;
            }
        }
    }
}

// ---------------------------------------------------------------------------
// Fallback (proven R1 kernel) if ws_size can't hold packed K/V.
// ---------------------------------------------------------------------------
__global__ __launch_bounds__(256, 2)
void usp_attn_fa(const float* __restrict__ Q, const float* __restrict__ K,
                 const float* __restrict__ V, float* __restrict__ O) {
    __shared__ unsigned short fK[BK * LK];
    __shared__ unsigned short fVT[D_ * LK];
    __shared__ unsigned short fP[4 * 16 * LP];
    const int tid = threadIdx.x;
    const int lane = tid & 63;
    const int wv = tid >> 6;
    const int h = blockIdx.x & (H_ - 1);
    const int qt = blockIdx.x >> 4;
    const int q0 = qt * 64 + wv * 16;
    const int m16 = lane & 15;
    const int g = lane >> 4;
    typedef __attribute__((ext_vector_type(4))) float f4;
    bf16x8 qf[2];
    {
        const float* qp = Q + (size_t)(q0 + m16) * ROWSTRIDE + h * D_ + g * 8;
        for (int c = 0; c < 2; ++c) {
            ushortx8 u;
            #pragma unroll
            for (int j = 0; j < 8; ++j) u[j] = f2bf(qp[c * 32 + j]);
            qf[c] = as_bf16x8(u);
        }
    }
    f4 o[4] = {{0,0,0,0},{0,0,0,0},{0,0,0,0},{0,0,0,0}};
    float mrow[4] = {-1e30f,-1e30f,-1e30f,-1e30f};
    float lrow[4] = {0.f,0.f,0.f,0.f};
    unsigned short* myP = &fP[wv * 16 * LP];
    for (int k0 = 0; k0 < S_; k0 += BK) {
        __syncthreads();
        #pragma unroll
        for (int p = 0; p < 4; ++p) {
            int idx = tid + p * 256;
            int row = idx >> 4;
            int c4 = (idx & 15) * 4;
            const float* kp = K + (size_t)(k0 + row) * ROWSTRIDE + h * D_ + c4;
            float4 kv = *(const float4*)kp;
            ushortx4 ku;
            ku[0] = f2bf(kv.x); ku[1] = f2bf(kv.y); ku[2] = f2bf(kv.z); ku[3] = f2bf(kv.w);
            *(ushortx4*)&fK[row * LK + c4] = ku;
            const float* vp = V + (size_t)(k0 + row) * ROWSTRIDE + h * D_ + c4;
            float4 vv = *(const float4*)vp;
            fVT[(c4 + 0) * LK + row] = f2bf(vv.x);
            fVT[(c4 + 1) * LK + row] = f2bf(vv.y);
            fVT[(c4 + 2) * LK + row] = f2bf(vv.z);
            fVT[(c4 + 3) * LK + row] = f2bf(vv.w);
        }
        __syncthreads();
        f4 s[4];
        #pragma unroll
        for (int t = 0; t < 4; ++t) {
            f4 acc = {0,0,0,0};
            #pragma unroll
            for (int c = 0; c < 2; ++c) {
                bf16x8 kf = as_bf16x8(*(ushortx8*)&fK[(t * 16 + m16) * LK + c * 32 + g * 8]);
                acc = __builtin_amdgcn_mfma_f32_16x16x32_bf16(qf[c], kf, acc, 0, 0, 0);
            }
            s[t] = acc * SM_SCALE;
        }
        float mnew[4], rsum[4];
        #pragma unroll
        for (int r = 0; r < 4; ++r) {
            float pm = fmaxf(fmaxf(s[0][r], s[1][r]), fmaxf(s[2][r], s[3][r]));
            #pragma unroll
            for (int msk = 1; msk <= 8; msk <<= 1) pm = fmaxf(pm, __shfl_xor(pm, msk, 64));
            mnew[r] = fmaxf(mrow[r], pm);
            rsum[r] = 0.f;
        }
        #pragma unroll
        for (int t = 0; t < 4; ++t) {
            #pragma unroll
            for (int r = 0; r < 4; ++r) {
                float p = EXP2F((s[t][r] - mnew[r]) * LOG2E);
                rsum[r] += p;
                myP[(g * 4 + r) * LP + t * 16 + m16] = f2bf(p);
            }
        }
        #pragma unroll
        for (int r = 0; r < 4; ++r) {
            #pragma unroll
            for (int msk = 1; msk <= 8; msk <<= 1) rsum[r] += __shfl_xor(rsum[r], msk, 64);
            float alpha = EXP2F((mrow[r] - mnew[r]) * LOG2E);
            lrow[r] = lrow[r] * alpha + rsum[r];
            mrow[r] = mnew[r];
            o[0][r] *= alpha; o[1][r] *= alpha; o[2][r] *= alpha; o[3][r] *= alpha;
        }
        #pragma unroll
        for (int c = 0; c < 2; ++c) {
            bf16x8 pf = as_bf16x8(*(ushortx8*)&myP[m16 * LP + c * 32 + g * 8]);
            #pragma unroll
            for (int t = 0; t < 4; ++t) {
                bf16x8 vf = as_bf16x8(*(ushortx8*)&fVT[(t * 16 + m16) * LK + c * 32 + g * 8]);
                o[t] = __builtin_amdgcn_mfma_f32_16x16x32_bf16(pf, vf, o[t], 0, 0, 0);
            }
        }
    }
    float* op = O + (size_t)q0 * ROWSTRIDE + h * D_;
    #pragma unroll
    for (int r = 0; r < 4; ++r) {
        float inv = 1.f / lrow[r];
        int row = g * 4 + r;
        #pragma unroll
        for (int t = 0; t < 4; ++t)
            op[(size_t)row * ROWSTRIDE + t * 16 + m16] = o[t][r] * inv;
    }
}

extern "C" void kernel_launch(void* const* d_in, const int* in_sizes, int n_in,
                              void* d_out, int out_size, void* d_ws, size_t ws_size,
                              hipStream_t stream) {
    const float* Q = (const float*)d_in[0];
    const float* K = (const float*)d_in[1];
    const float* V = (const float*)d_in[2];
    float* O = (float*)d_out;
    const size_t packed = (size_t)H_ * NT * TILE_USH;
    if (ws_size >= 2 * packed * sizeof(ushort_t)) {
        ushort_t* Kp = (ushort_t*)d_ws;
        ushort_t* Vp = Kp + packed;
        pack_kv<<<dim3(H_ * NT), dim3(256), 0, stream>>>(K, V, Kp, Vp);
        usp_attn_fa4<<<dim3(H_ * (S_ / BQ)), dim3(256), 0, stream>>>(Q, Kp, Vp, O);
    } else {
        usp_attn_fa<<<dim3(H_ * (S_ / 64)), dim3(256), 0, stream>>>(Q, K, V, O);
    }
}